// Round 1
// baseline (1317.290 us; speedup 1.0000x reference)
//
#include <hip/hip_runtime.h>

#define N_NODES 20000
#define FEAT    128
#define SEQ     32
#define HEADS   4
#define HDIM    32
#define NT      8      // nodes per block
#define RS      132    // padded LDS row stride for 128-float rows (132*4B, float4-aligned rows)

__device__ __forceinline__ void fma4(float4& a, float s, const float4 b) {
    a.x = fmaf(s, b.x, a.x);
    a.y = fmaf(s, b.y, a.y);
    a.z = fmaf(s, b.z, a.z);
    a.w = fmaf(s, b.w, a.w);
}

__device__ __forceinline__ float dot4(const float4 a, const float4 b) {
    return fmaf(a.x, b.x, fmaf(a.y, b.y, fmaf(a.z, b.z, a.w * b.w)));
}

// Prep: WkT[c][f] = Wk[f][c]  (64 KB, ~2 us, coalesced column access in P2)
__global__ void transpose_wk(const float* __restrict__ Wk, float* __restrict__ WkT) {
    int tid = blockIdx.x * blockDim.x + threadIdx.x;   // 0..16383
    int c = tid >> 7, f = tid & 127;
    WkT[c * 128 + f] = Wk[f * 128 + c];
}

__global__ __launch_bounds__(256, 5) void mha_fused(
    const float* __restrict__ query, const float* __restrict__ key,
    const float* __restrict__ value, const int* __restrict__ mask_idx,
    const float* __restrict__ Wq, const float* __restrict__ bq,
    const float* __restrict__ WkT, const float* __restrict__ bk,
    const float* __restrict__ Wv, const float* __restrict__ bv,
    const float* __restrict__ Wo, const float* __restrict__ bo,
    const float* __restrict__ gamma, const float* __restrict__ beta,
    float* __restrict__ out)
{
    __shared__ __align__(16) float qT[NT * RS];        // query tile (live until residual)
    __shared__ __align__(16) float qh[NT * RS];        // qhat; later reused as wv
    __shared__ __align__(16) float av[NT * 4 * RS];    // attn-weighted raw value, P4->P5
    __shared__ __align__(16) float sc2[NT * SEQ * 4];  // scores/attn, layout [nd][s][h] (h contiguous)
    __shared__ float qbk[NT * 4];
    __shared__ int   Ls[NT];                           // live seq length per node (mi==0 -> 32)
    __shared__ int   Mi[NT];

    const int tid   = threadIdx.x;
    const int node0 = blockIdx.x * NT;
    const int ng = tid >> 5;               // node slot 0..7
    const int f4 = tid & 31;               // feature quad 0..31
    const int fo = f4 * 4;

    // ---------- P0: load query tile (coalesced float4) + mask lengths ----------
    {
        int i  = tid * 4;                  // flat 0..1023
        int nd = i >> 7, f = i & 127;
        float4 v = *(const float4*)&query[(long)(node0 + nd) * FEAT + f];
        *(float4*)&qT[nd * RS + f] = v;
        if (tid < NT) {
            int m = mask_idx[node0 + tid];
            Mi[tid] = m;
            Ls[tid] = (m == 0) ? SEQ : m;  // mi==0: uniform -1e9 shift, all positions live
        }
    }
    __syncthreads();

    // ---------- P1: qhat = query @ Wq + bq  (b128 LDS broadcasts, same fp32 sum order) ----------
    {
        float4 acc = {0.f, 0.f, 0.f, 0.f};
        for (int c4 = 0; c4 < 32; ++c4) {
            float4 qv = *(const float4*)&qT[ng * RS + c4 * 4];
            const float* wp = &Wq[c4 * 4 * 128 + fo];
            fma4(acc, qv.x, *(const float4*)&wp[0]);
            fma4(acc, qv.y, *(const float4*)&wp[128]);
            fma4(acc, qv.z, *(const float4*)&wp[256]);
            fma4(acc, qv.w, *(const float4*)&wp[384]);
        }
        float4 b = *(const float4*)&bq[fo];
        acc.x += b.x; acc.y += b.y; acc.z += b.z; acc.w += b.w;
        *(float4*)&qh[ng * RS + fo] = acc;
    }
    __syncthreads();

    // ---------- P2: qk[ng][h][fo..fo+3] kept in REGISTERS (no qkav LDS round-trip) ----------
    float4 qkr[4];
    {
        #pragma unroll
        for (int h = 0; h < 4; ++h) {
            float4 acc = {0.f, 0.f, 0.f, 0.f};
            #pragma unroll
            for (int d4 = 0; d4 < 8; ++d4) {
                float4 qv = *(const float4*)&qh[ng * RS + h * 32 + d4 * 4];
                const float* wp = &WkT[(h * 32 + d4 * 4) * 128 + fo];
                fma4(acc, qv.x, *(const float4*)&wp[0]);
                fma4(acc, qv.y, *(const float4*)&wp[128]);
                fma4(acc, qv.z, *(const float4*)&wp[256]);
                fma4(acc, qv.w, *(const float4*)&wp[384]);
            }
            qkr[h] = acc;
        }
    }
    if (tid < 32) {   // qbk[nd*4+h] = qhat[nd][h-slice] . bk[h-slice]
        int nd = tid >> 2, h = tid & 3;
        float s = 0.f;
        for (int d = 0; d < 32; ++d)
            s = fmaf(qh[nd * RS + h * 32 + d], bk[h * 32 + d], s);
        qbk[tid] = s;
    }
    // no barrier: P3 consumes only this thread's registers + P0 data (already synced)

    // ---------- P3: scores for live rows only; zero LDS reads; 6-shuffle reduce ----------
    // Lane f4 holds 4 features of key row s and all 4 heads' qk fragments.
    // Reduce 4 head-dots across 32 lanes: 2 distribute stages + 3 butterfly stages.
    {
        const int L = Ls[ng];
        const long kbase = (long)(node0 + ng) * FEAT + fo;
        const int b0 = f4 & 1;
        const int b1 = f4 & 2;
        for (int s = 0; s < L; ++s) {
            float4 k4 = *(const float4*)&key[kbase + (long)s * (N_NODES * FEAT)];
            float p0 = dot4(k4, qkr[0]);
            float p1 = dot4(k4, qkr[1]);
            float p2 = dot4(k4, qkr[2]);
            float p3 = dot4(k4, qkr[3]);
            // stage 1 (xor 1): fold h-pairs; lane bit0 selects which h it keeps
            float ra = __shfl_xor(b0 ? p0 : p1, 1);
            float rb = __shfl_xor(b0 ? p2 : p3, 1);
            float q0 = (b0 ? p1 : p0) + ra;      // h = b0
            float q1 = (b0 ? p3 : p2) + rb;      // h = 2 + b0
            // stage 2 (xor 2): lane%4 == h afterwards
            float rc = __shfl_xor(b1 ? q0 : q1, 2);
            float u  = (b1 ? q1 : q0) + rc;      // h = f4 & 3 (4-lane group sum)
            // butterfly over remaining lanes (stays within 32-lane half-wave)
            u += __shfl_xor(u, 4);
            u += __shfl_xor(u, 8);
            u += __shfl_xor(u, 16);
            if (f4 < 4) sc2[(ng * SEQ + s) * 4 + f4] = u;   // raw score, h = f4
        }
    }
    __syncthreads();

    // ---------- P3b: softmax over live positions, all 256 threads (identical fp32 ops) ----------
    {
        const int pair  = tid >> 3;          // nd*4+h
        const int lane8 = tid & 7;
        const int nd = pair >> 2;
        const int h  = pair & 3;
        const int L  = Ls[nd];
        const bool mi0 = (Mi[nd] == 0);
        const float qb = qbk[pair];
        const float scale = 0.17677669529663687f;   // 1/sqrt(32)
        float v[4];
        #pragma unroll
        for (int i = 0; i < 4; ++i) {
            int s2 = lane8 * 4 + i;
            if (s2 < L) {
                float t = (sc2[(nd * SEQ + s2) * 4 + h] + qb) * scale;
                if (mi0) t += -1e9f;        // same fp32 op order as verified kernel
                v[i] = t;
            } else v[i] = -3.0e38f;
        }
        float mx = fmaxf(fmaxf(v[0], v[1]), fmaxf(v[2], v[3]));
        mx = fmaxf(mx, __shfl_xor(mx, 1));
        mx = fmaxf(mx, __shfl_xor(mx, 2));
        mx = fmaxf(mx, __shfl_xor(mx, 4));
        float e[4], sum = 0.f;
        #pragma unroll
        for (int i = 0; i < 4; ++i) {
            int s2 = lane8 * 4 + i;
            e[i] = (s2 < L) ? __expf(v[i] - mx) : 0.f;
            sum += e[i];
        }
        sum += __shfl_xor(sum, 1);
        sum += __shfl_xor(sum, 2);
        sum += __shfl_xor(sum, 4);
        const float inv = 1.f / sum;
        #pragma unroll
        for (int i = 0; i < 4; ++i) {
            int s2 = lane8 * 4 + i;
            if (s2 < L) sc2[(nd * SEQ + s2) * 4 + h] = e[i] * inv;
        }
    }
    __syncthreads();

    // ---------- P4: av[ng][h][f] = sum_{s<L} attn[ng][h][s] * value[s,node,f] ----------
    // attn for all 4 heads arrives as ONE broadcast float4 per s.
    {
        float4 acc[4];
        #pragma unroll
        for (int h = 0; h < 4; ++h) acc[h] = make_float4(0.f, 0.f, 0.f, 0.f);
        const long vbase = (long)(node0 + ng) * FEAT + fo;
        const int L = Ls[ng];
        for (int s2 = 0; s2 < L; ++s2) {
            float4 vv = *(const float4*)&value[vbase + (long)s2 * (N_NODES * FEAT)];
            float4 a4 = *(const float4*)&sc2[(ng * SEQ + s2) * 4];
            fma4(acc[0], a4.x, vv);
            fma4(acc[1], a4.y, vv);
            fma4(acc[2], a4.z, vv);
            fma4(acc[3], a4.w, vv);
        }
        #pragma unroll
        for (int h = 0; h < 4; ++h)
            *(float4*)&av[(ng * 4 + h) * RS + fo] = acc[h];
    }
    __syncthreads();

    // ---------- P5: wv[ng][o] = sum_f av[ng][h(o)][f] * Wv[f][o] + bv[o] ----------
    {
        const int h = fo >> 5;
        float4 acc = {0.f, 0.f, 0.f, 0.f};
        for (int g = 0; g < 32; ++g) {
            float4 a4 = *(const float4*)&av[(ng * 4 + h) * RS + g * 4];
            const float* wp = &Wv[g * 4 * 128 + fo];
            fma4(acc, a4.x, *(const float4*)&wp[0]);
            fma4(acc, a4.y, *(const float4*)&wp[128]);
            fma4(acc, a4.z, *(const float4*)&wp[256]);
            fma4(acc, a4.w, *(const float4*)&wp[384]);
        }
        float4 b = *(const float4*)&bv[fo];
        acc.x += b.x; acc.y += b.y; acc.z += b.z; acc.w += b.w;
        *(float4*)&qh[ng * RS + fo] = acc;    // qh (qhat) dead since P3b barrier; reuse as wv
    }
    __syncthreads();

    // ---------- P6+P7: out = LN(wv @ Wo + bo) + query, all in registers ----------
    {
        float4 x = {0.f, 0.f, 0.f, 0.f};
        for (int c4 = 0; c4 < 32; ++c4) {
            float4 wv4 = *(const float4*)&qh[ng * RS + c4 * 4];
            const float* wp = &Wo[c4 * 4 * 128 + fo];
            fma4(x, wv4.x, *(const float4*)&wp[0]);
            fma4(x, wv4.y, *(const float4*)&wp[128]);
            fma4(x, wv4.z, *(const float4*)&wp[256]);
            fma4(x, wv4.w, *(const float4*)&wp[384]);
        }
        float4 b = *(const float4*)&bo[fo];
        x.x += b.x; x.y += b.y; x.z += b.z; x.w += b.w;

        float s1 = x.x + x.y + x.z + x.w;
        float s2 = x.x * x.x + x.y * x.y + x.z * x.z + x.w * x.w;
        #pragma unroll
        for (int off = 1; off < 32; off <<= 1) {
            s1 += __shfl_xor(s1, off);
            s2 += __shfl_xor(s2, off);
        }
        const float mu  = s1 * (1.f / 128.f);
        const float var = s2 * (1.f / 128.f) - mu * mu;
        const float rstd = rsqrtf(var + 1e-5f);
        float4 g = *(const float4*)&gamma[fo];
        float4 bt = *(const float4*)&beta[fo];
        float4 q = *(float4*)&qT[ng * RS + fo];
        float4 r;
        r.x = (x.x - mu) * rstd * g.x + bt.x + q.x;
        r.y = (x.y - mu) * rstd * g.y + bt.y + q.y;
        r.z = (x.z - mu) * rstd * g.z + bt.z + q.z;
        r.w = (x.w - mu) * rstd * g.w + bt.w + q.w;
        *(float4*)&out[(long)(node0 + ng) * FEAT + fo] = r;
    }
}

extern "C" void kernel_launch(void* const* d_in, const int* in_sizes, int n_in,
                              void* d_out, int out_size, void* d_ws, size_t ws_size,
                              hipStream_t stream) {
    const float* query = (const float*)d_in[0];
    const float* key   = (const float*)d_in[1];
    const float* value = (const float*)d_in[2];
    const int*   midx  = (const int*)  d_in[3];
    const float* Wq    = (const float*)d_in[4];
    const float* bq    = (const float*)d_in[5];
    const float* Wk    = (const float*)d_in[6];
    const float* bk    = (const float*)d_in[7];
    const float* Wv    = (const float*)d_in[8];
    const float* bv    = (const float*)d_in[9];
    const float* Wo    = (const float*)d_in[10];
    const float* bo    = (const float*)d_in[11];
    const float* gamma = (const float*)d_in[12];
    const float* beta  = (const float*)d_in[13];

    float* WkT = (float*)d_ws;   // 64 KB scratch, rewritten every launch

    transpose_wk<<<64, 256, 0, stream>>>(Wk, WkT);
    mha_fused<<<N_NODES / NT, 256, 0, stream>>>(
        query, key, value, midx, Wq, bq, WkT, bk, Wv, bv, Wo, bo,
        gamma, beta, (float*)d_out);
}

// Round 2
// 698.072 us; speedup vs baseline: 1.8870x; 1.8870x over previous
//
#include <hip/hip_runtime.h>

#define N_NODES 20000
#define FEAT    128
#define SEQ     32
#define HEADS   4
#define HDIM    32
#define NT      8      // nodes per block
#define RS      132    // padded LDS row stride for 128-float rows (132*4B, float4-aligned rows)

__device__ __forceinline__ void fma4(float4& a, float s, const float4 b) {
    a.x = fmaf(s, b.x, a.x);
    a.y = fmaf(s, b.y, a.y);
    a.z = fmaf(s, b.z, a.z);
    a.w = fmaf(s, b.w, a.w);
}

__device__ __forceinline__ float dot4(const float4 a, const float4 b) {
    return fmaf(a.x, b.x, fmaf(a.y, b.y, fmaf(a.z, b.z, a.w * b.w)));
}

// cross K-half combine: lanes tid and tid^32 hold the two halves of the same sums
__device__ __forceinline__ float4 xsum32(float4 a) {
    a.x += __shfl_xor(a.x, 32);
    a.y += __shfl_xor(a.y, 32);
    a.z += __shfl_xor(a.z, 32);
    a.w += __shfl_xor(a.w, 32);
    return a;
}

// Prep: WkT[c][f] = Wk[f][c]  (64 KB, ~2 us, coalesced column access in P2)
__global__ void transpose_wk(const float* __restrict__ Wk, float* __restrict__ WkT) {
    int tid = blockIdx.x * blockDim.x + threadIdx.x;   // 0..16383
    int c = tid >> 7, f = tid & 127;
    WkT[c * 128 + f] = Wk[f * 128 + c];
}

__global__ __launch_bounds__(256, 4) void mha_fused(
    const float* __restrict__ query, const float* __restrict__ key,
    const float* __restrict__ value, const int* __restrict__ mask_idx,
    const float* __restrict__ Wq, const float* __restrict__ bq,
    const float* __restrict__ WkT, const float* __restrict__ bk,
    const float* __restrict__ Wv, const float* __restrict__ bv,
    const float* __restrict__ Wo, const float* __restrict__ bo,
    const float* __restrict__ gamma, const float* __restrict__ beta,
    float* __restrict__ out)
{
    __shared__ __align__(16) float qT[NT * RS];        // query tile (live until residual)
    __shared__ __align__(16) float qh[NT * RS];        // qhat; later reused as wv
    __shared__ __align__(16) float av[NT * 4 * RS];    // attn-weighted raw value, P4->P5
    __shared__ __align__(16) float sc2[NT * SEQ * 4];  // scores/attn, layout [nd][s][h]
    __shared__ float qbk[NT * 4];
    __shared__ int   Ls[NT];                           // live seq length per node (mi==0 -> 32)
    __shared__ int   Mi[NT];

    const int tid   = threadIdx.x;
    const int node0 = blockIdx.x * NT;
    const int g   = tid >> 5;          // 32-lane group 0..7
    const int kh  = g & 1;             // K-half (0: c<64, 1: c>=64)
    const int nd0 = g & ~1;            // even node of this pair
    const int f4  = tid & 31;          // feature quad 0..31
    const int fo  = f4 * 4;
    const long kstride = (long)N_NODES * FEAT;

    // ---------- P0: load query tile (coalesced float4) + mask lengths ----------
    {
        int i  = tid * 4;                  // flat 0..1023
        int nd = i >> 7, f = i & 127;
        float4 v = *(const float4*)&query[(long)(node0 + nd) * FEAT + f];
        *(float4*)&qT[nd * RS + f] = v;
        if (tid < NT) {
            int m = mask_idx[node0 + tid];
            Mi[tid] = m;
            Ls[tid] = (m == 0) ? SEQ : m;  // mi==0: uniform -1e9 shift, all positions live
        }
    }
    __syncthreads();

    // ---------- P1: qhat = query @ Wq + bq  (pair-of-nodes x K-half split) ----------
    {
        float4 a0 = {0.f,0.f,0.f,0.f}, a1 = {0.f,0.f,0.f,0.f};
        const int cbase = kh * 64;
        for (int c4 = 0; c4 < 16; ++c4) {
            const int c = cbase + c4 * 4;
            const float4 q0 = *(const float4*)&qT[nd0 * RS + c];
            const float4 q1 = *(const float4*)&qT[(nd0 + 1) * RS + c];
            const float* wp = &Wq[c * 128 + fo];
            const float4 w0 = *(const float4*)&wp[0];
            const float4 w1 = *(const float4*)&wp[128];
            const float4 w2 = *(const float4*)&wp[256];
            const float4 w3 = *(const float4*)&wp[384];
            fma4(a0, q0.x, w0); fma4(a1, q1.x, w0);
            fma4(a0, q0.y, w1); fma4(a1, q1.y, w1);
            fma4(a0, q0.z, w2); fma4(a1, q1.z, w2);
            fma4(a0, q0.w, w3); fma4(a1, q1.w, w3);
        }
        a0 = xsum32(a0); a1 = xsum32(a1);
        float4 r = kh ? a1 : a0;
        const float4 b = *(const float4*)&bq[fo];
        r.x += b.x; r.y += b.y; r.z += b.z; r.w += b.w;
        *(float4*)&qh[(nd0 + kh) * RS + fo] = r;
    }
    __syncthreads();   // qh consumed cross-wave by qbk (tid<32)

    // ---------- P2: qk fragments in REGISTERS for node nd0+kh (pair x half-of-d split) ----------
    float4 qkr[4];
    {
        #pragma unroll
        for (int h = 0; h < 4; ++h) {
            float4 a0 = {0.f,0.f,0.f,0.f}, a1 = {0.f,0.f,0.f,0.f};
            #pragma unroll
            for (int d4 = 0; d4 < 4; ++d4) {
                const int idx = h * 32 + kh * 16 + d4 * 4;
                const float4 q0 = *(const float4*)&qh[nd0 * RS + idx];
                const float4 q1 = *(const float4*)&qh[(nd0 + 1) * RS + idx];
                const float* wp = &WkT[idx * 128 + fo];
                const float4 w0 = *(const float4*)&wp[0];
                const float4 w1 = *(const float4*)&wp[128];
                const float4 w2 = *(const float4*)&wp[256];
                const float4 w3 = *(const float4*)&wp[384];
                fma4(a0, q0.x, w0); fma4(a1, q1.x, w0);
                fma4(a0, q0.y, w1); fma4(a1, q1.y, w1);
                fma4(a0, q0.z, w2); fma4(a1, q1.z, w2);
                fma4(a0, q0.w, w3); fma4(a1, q1.w, w3);
            }
            a0 = xsum32(a0); a1 = xsum32(a1);
            qkr[h] = kh ? a1 : a0;
        }
    }
    if (tid < 32) {   // qbk[nd*4+h] = qhat[nd][h-slice] . bk[h-slice] (exact serial order)
        int nd = tid >> 2, h = tid & 3;
        float s = 0.f;
        for (int d = 0; d < 32; ++d)
            s = fmaf(qh[nd * RS + h * 32 + d], bk[h * 32 + d], s);
        qbk[tid] = s;
    }
    // no barrier: P3 consumes only this group's registers + P0 data (already synced)

    // ---------- P3: scores for node nd0+kh, live rows only, 2-deep prefetch ----------
    {
        const int nd = nd0 + kh;
        const int L  = Ls[nd];
        const long kbase = (long)(node0 + nd) * FEAT + fo;
        const int b0 = f4 & 1;
        const int b1 = f4 & 2;
        float4 kA = *(const float4*)&key[kbase];       // L >= 1 always
        float4 kB = kA;
        if (L > 1) kB = *(const float4*)&key[kbase + kstride];
        for (int s = 0; s < L; ++s) {
            const float4 k4 = kA;
            kA = kB;
            if (s + 2 < L) kB = *(const float4*)&key[kbase + (long)(s + 2) * kstride];
            float p0 = dot4(k4, qkr[0]);
            float p1 = dot4(k4, qkr[1]);
            float p2 = dot4(k4, qkr[2]);
            float p3 = dot4(k4, qkr[3]);
            // stage 1 (xor 1): fold h-pairs
            float ra = __shfl_xor(b0 ? p0 : p1, 1);
            float rb = __shfl_xor(b0 ? p2 : p3, 1);
            float q0 = (b0 ? p1 : p0) + ra;      // h = b0
            float q1 = (b0 ? p3 : p2) + rb;      // h = 2 + b0
            // stage 2 (xor 2): lane%4 == h afterwards
            float rc = __shfl_xor(b1 ? q0 : q1, 2);
            float u  = (b1 ? q1 : q0) + rc;
            // butterfly within 32-lane half
            u += __shfl_xor(u, 4);
            u += __shfl_xor(u, 8);
            u += __shfl_xor(u, 16);
            if (f4 < 4) sc2[(nd * SEQ + s) * 4 + f4] = u;   // raw score, h = f4
        }
    }
    __syncthreads();   // covers qbk (wave0) -> P3b (all waves)

    // ---------- P3b: softmax, node = tid>>5 handled by its own 32-lane group ----------
    {
        const int pair  = tid >> 3;          // nd*4+h
        const int lane8 = tid & 7;
        const int nd = pair >> 2;            // == tid>>5 (same group as producer)
        const int h  = pair & 3;
        const int L  = Ls[nd];
        const bool mi0 = (Mi[nd] == 0);
        const float qb = qbk[pair];
        const float scale = 0.17677669529663687f;   // 1/sqrt(32)
        float v[4];
        #pragma unroll
        for (int i = 0; i < 4; ++i) {
            int s2 = lane8 * 4 + i;
            if (s2 < L) {
                float t = (sc2[(nd * SEQ + s2) * 4 + h] + qb) * scale;
                if (mi0) t += -1e9f;        // exact fp32 op order (verified numerics)
                v[i] = t;
            } else v[i] = -3.0e38f;
        }
        float mx = fmaxf(fmaxf(v[0], v[1]), fmaxf(v[2], v[3]));
        mx = fmaxf(mx, __shfl_xor(mx, 1));
        mx = fmaxf(mx, __shfl_xor(mx, 2));
        mx = fmaxf(mx, __shfl_xor(mx, 4));
        float e[4], sum = 0.f;
        #pragma unroll
        for (int i = 0; i < 4; ++i) {
            int s2 = lane8 * 4 + i;
            e[i] = (s2 < L) ? __expf(v[i] - mx) : 0.f;
            sum += e[i];
        }
        sum += __shfl_xor(sum, 1);
        sum += __shfl_xor(sum, 2);
        sum += __shfl_xor(sum, 4);
        const float inv = 1.f / sum;
        #pragma unroll
        for (int i = 0; i < 4; ++i) {
            int s2 = lane8 * 4 + i;
            if (s2 < L) sc2[(nd * SEQ + s2) * 4 + h] = e[i] * inv;
        }
    }
    // no barrier: P4's node == tid>>5 — same 32-lane group produced its attn (intra-wave dep)

    // ---------- P4: av[g][h][f] = sum_{s<L} attn[g][h][s] * value[s,node,f], 2-deep prefetch ----------
    {
        float4 acc[4];
        #pragma unroll
        for (int h = 0; h < 4; ++h) acc[h] = make_float4(0.f, 0.f, 0.f, 0.f);
        const long vbase = (long)(node0 + g) * FEAT + fo;
        const int L = Ls[g];
        float4 vA = *(const float4*)&value[vbase];
        float4 vB = vA;
        if (L > 1) vB = *(const float4*)&value[vbase + kstride];
        for (int s2 = 0; s2 < L; ++s2) {
            const float4 vv = vA;
            vA = vB;
            if (s2 + 2 < L) vB = *(const float4*)&value[vbase + (long)(s2 + 2) * kstride];
            const float4 a4 = *(const float4*)&sc2[(g * SEQ + s2) * 4];
            fma4(acc[0], a4.x, vv);
            fma4(acc[1], a4.y, vv);
            fma4(acc[2], a4.z, vv);
            fma4(acc[3], a4.w, vv);
        }
        #pragma unroll
        for (int h = 0; h < 4; ++h)
            *(float4*)&av[(g * 4 + h) * RS + fo] = acc[h];
    }
    // no barrier: P5 reads av rows of nodes nd0,nd0+1 — written by groups g=nd0,nd0+1 (same wave)

    // ---------- P5: wv = av @ Wv + bv  (pair x K-half split) ----------
    {
        const int h = fo >> 5;
        float4 a0 = {0.f,0.f,0.f,0.f}, a1 = {0.f,0.f,0.f,0.f};
        const int fbase = kh * 64;
        for (int g4 = 0; g4 < 16; ++g4) {
            const int f = fbase + g4 * 4;
            const float4 x0 = *(const float4*)&av[(nd0 * 4 + h) * RS + f];
            const float4 x1 = *(const float4*)&av[((nd0 + 1) * 4 + h) * RS + f];
            const float* wp = &Wv[f * 128 + fo];
            const float4 w0 = *(const float4*)&wp[0];
            const float4 w1 = *(const float4*)&wp[128];
            const float4 w2 = *(const float4*)&wp[256];
            const float4 w3 = *(const float4*)&wp[384];
            fma4(a0, x0.x, w0); fma4(a1, x1.x, w0);
            fma4(a0, x0.y, w1); fma4(a1, x1.y, w1);
            fma4(a0, x0.z, w2); fma4(a1, x1.z, w2);
            fma4(a0, x0.w, w3); fma4(a1, x1.w, w3);
        }
        a0 = xsum32(a0); a1 = xsum32(a1);
        float4 r = kh ? a1 : a0;
        const float4 b = *(const float4*)&bv[fo];
        r.x += b.x; r.y += b.y; r.z += b.z; r.w += b.w;
        *(float4*)&qh[(nd0 + kh) * RS + fo] = r;   // qh (qhat) dead; reuse as wv
    }
    // no barrier: P6 reads qh rows nd0,nd0+1 — written by this same wave

    // ---------- P6+P7: out = LN(wv @ Wo + bo) + query (pair x K-half split) ----------
    {
        float4 a0 = {0.f,0.f,0.f,0.f}, a1 = {0.f,0.f,0.f,0.f};
        const int cbase = kh * 64;
        for (int c4 = 0; c4 < 16; ++c4) {
            const int c = cbase + c4 * 4;
            const float4 y0 = *(const float4*)&qh[nd0 * RS + c];
            const float4 y1 = *(const float4*)&qh[(nd0 + 1) * RS + c];
            const float* wp = &Wo[c * 128 + fo];
            const float4 w0 = *(const float4*)&wp[0];
            const float4 w1 = *(const float4*)&wp[128];
            const float4 w2 = *(const float4*)&wp[256];
            const float4 w3 = *(const float4*)&wp[384];
            fma4(a0, y0.x, w0); fma4(a1, y1.x, w0);
            fma4(a0, y0.y, w1); fma4(a1, y1.y, w1);
            fma4(a0, y0.z, w2); fma4(a1, y1.z, w2);
            fma4(a0, y0.w, w3); fma4(a1, y1.w, w3);
        }
        a0 = xsum32(a0); a1 = xsum32(a1);
        float4 x = kh ? a1 : a0;                  // this half's node: nd0+kh
        const int node = nd0 + kh;
        const float4 b = *(const float4*)&bo[fo];
        x.x += b.x; x.y += b.y; x.z += b.z; x.w += b.w;

        float s1 = x.x + x.y + x.z + x.w;
        float s2 = x.x * x.x + x.y * x.y + x.z * x.z + x.w * x.w;
        #pragma unroll
        for (int off = 1; off < 32; off <<= 1) {   // stays within the 32-lane half
            s1 += __shfl_xor(s1, off);
            s2 += __shfl_xor(s2, off);
        }
        const float mu  = s1 * (1.f / 128.f);
        const float var = s2 * (1.f / 128.f) - mu * mu;
        const float rstd = rsqrtf(var + 1e-5f);
        const float4 gm = *(const float4*)&gamma[fo];
        const float4 bt = *(const float4*)&beta[fo];
        const float4 q  = *(const float4*)&qT[node * RS + fo];
        float4 r;
        r.x = (x.x - mu) * rstd * gm.x + bt.x + q.x;
        r.y = (x.y - mu) * rstd * gm.y + bt.y + q.y;
        r.z = (x.z - mu) * rstd * gm.z + bt.z + q.z;
        r.w = (x.w - mu) * rstd * gm.w + bt.w + q.w;
        *(float4*)&out[(long)(node0 + node) * FEAT + fo] = r;
    }
}

extern "C" void kernel_launch(void* const* d_in, const int* in_sizes, int n_in,
                              void* d_out, int out_size, void* d_ws, size_t ws_size,
                              hipStream_t stream) {
    const float* query = (const float*)d_in[0];
    const float* key   = (const float*)d_in[1];
    const float* value = (const float*)d_in[2];
    const int*   midx  = (const int*)  d_in[3];
    const float* Wq    = (const float*)d_in[4];
    const float* bq    = (const float*)d_in[5];
    const float* Wk    = (const float*)d_in[6];
    const float* bk    = (const float*)d_in[7];
    const float* Wv    = (const float*)d_in[8];
    const float* bv    = (const float*)d_in[9];
    const float* Wo    = (const float*)d_in[10];
    const float* bo    = (const float*)d_in[11];
    const float* gamma = (const float*)d_in[12];
    const float* beta  = (const float*)d_in[13];

    float* WkT = (float*)d_ws;   // 64 KB scratch, rewritten every launch

    transpose_wk<<<64, 256, 0, stream>>>(Wk, WkT);
    mha_fused<<<N_NODES / NT, 256, 0, stream>>>(
        query, key, value, midx, Wq, bq, WkT, bk, Wv, bv, Wo, bo,
        gamma, beta, (float*)d_out);
}